// Round 6
// baseline (150.224 us; speedup 1.0000x reference)
//
#include <hip/hip_runtime.h>
#include <hip/hip_bf16.h>
#include <math.h>

// Problem constants (B=1)
#define TT 512      // tokens = B*S
#define DD 1024     // model dim
#define FF 4096     // ffn dim
#define EE 8        // experts
#define RR 16       // lora rank
#define KKSEL 2     // top-k
#define SCALING 2.0f
#define EPSV 1e-6f
#define DFC 128     // delta kernel f-chunk

typedef unsigned short u16;
typedef short bhalf8 __attribute__((ext_vector_type(8)));
typedef float floatx4 __attribute__((ext_vector_type(4)));
typedef unsigned short u16x8 __attribute__((ext_vector_type(8)));

__device__ __forceinline__ u16 f2b(float f) {
    unsigned x = __builtin_bit_cast(unsigned, f);
    unsigned r = (x + 0x7fffu + ((x >> 16) & 1u)) >> 16;
    return (u16)r;
}
__device__ __forceinline__ float b2f(u16 b) {
    unsigned x = ((unsigned)b) << 16;
    return __builtin_bit_cast(float, x);
}

__device__ __forceinline__ void gl_lds16(const void* g, void* l) {
    __builtin_amdgcn_global_load_lds(
        (const __attribute__((address_space(1))) void*)g,
        (__attribute__((address_space(3))) void*)l, 16, 0, 0);
}

// ---------------- fp32 -> bf16 convert ----------------
__global__ __launch_bounds__(256) void f2b_k(const float* __restrict__ in,
                                             u16* __restrict__ out, int n) {
    int i = (blockIdx.x * 256 + threadIdx.x) * 4;
    int stride = gridDim.x * 256 * 4;
    for (; i < n; i += stride) {
        float4 v = *(const float4*)(in + i);
        ushort4 o = { f2b(v.x), f2b(v.y), f2b(v.z), f2b(v.w) };
        *(ushort4*)(out + i) = o;
    }
}

// ---------------- RMSNorm: x[T,D] -> t fp32 + bf16 ----------------
__global__ __launch_bounds__(256) void rmsnorm_k(const float* __restrict__ x,
                                                 const float* __restrict__ nw,
                                                 float* __restrict__ t,
                                                 u16* __restrict__ tb) {
    int tok = blockIdx.x;
    const float* xr = x + (size_t)tok * DD;
    float ss = 0.f;
    for (int d = threadIdx.x; d < DD; d += 256) { float v = xr[d]; ss += v * v; }
    __shared__ float red[4];
    #pragma unroll
    for (int o = 32; o > 0; o >>= 1) ss += __shfl_down(ss, o);
    int wave = threadIdx.x >> 6, lane = threadIdx.x & 63;
    if (lane == 0) red[wave] = ss;
    __syncthreads();
    if (threadIdx.x == 0) {
        float s = red[0] + red[1] + red[2] + red[3];
        red[0] = rsqrtf(s * (1.0f / DD) + EPSV);
    }
    __syncthreads();
    float rs = red[0];
    for (int d = threadIdx.x; d < DD; d += 256) {
        float v = xr[d] * rs * nw[d];
        t[(size_t)tok * DD + d] = v;
        tb[(size_t)tok * DD + d] = f2b(v);
    }
}

// ---------------- Router ----------------
__global__ __launch_bounds__(64) void router_k(const float* __restrict__ t,
                                               const float* __restrict__ gw,
                                               float* __restrict__ topw,
                                               int* __restrict__ topi) {
    int tok = blockIdx.x;
    int lane = threadIdx.x;
    const float* tr = t + (size_t)tok * DD;
    float acc[EE];
    #pragma unroll
    for (int e = 0; e < EE; e++) acc[e] = 0.f;
    for (int d = lane; d < DD; d += 64) {
        float tv = tr[d];
        #pragma unroll
        for (int e = 0; e < EE; e++) acc[e] = fmaf(tv, gw[(size_t)e * DD + d], acc[e]);
    }
    #pragma unroll
    for (int e = 0; e < EE; e++) {
        #pragma unroll
        for (int o = 32; o > 0; o >>= 1) acc[e] += __shfl_down(acc[e], o);
    }
    if (lane == 0) {
        float m = acc[0];
        #pragma unroll
        for (int e = 1; e < EE; e++) m = fmaxf(m, acc[e]);
        float p[EE];
        #pragma unroll
        for (int e = 0; e < EE; e++) p[e] = expf(acc[e] - m);
        int i0 = 0; float v0 = p[0];
        for (int e = 1; e < EE; e++) if (p[e] > v0) { v0 = p[e]; i0 = e; }
        int i1 = -1; float v1 = -1.f;
        for (int e = 0; e < EE; e++) { if (e == i0) continue; if (p[e] > v1) { v1 = p[e]; i1 = e; } }
        float inv = 1.f / (v0 + v1);
        topi[tok * KKSEL + 0] = i0;
        topi[tok * KKSEL + 1] = i1;
        topw[tok * KKSEL + 0] = v0 * inv;
        topw[tok * KKSEL + 1] = v1 * inv;
    }
}

// ---------------- bucket slots by expert ----------------
__global__ __launch_bounds__(256) void build_lists_k(const int* __restrict__ topi,
                                                     int* __restrict__ lists,
                                                     int* __restrict__ counts) {
    __shared__ int cnt[EE];
    int tid = threadIdx.x;
    if (tid < EE) cnt[tid] = 0;
    __syncthreads();
    for (int s = tid; s < TT * KKSEL; s += 256) atomicAdd(&cnt[topi[s]], 1);
    __syncthreads();
    if (tid < EE) { counts[tid] = cnt[tid]; cnt[tid] = 0; }
    __syncthreads();
    for (int s = tid; s < TT * KKSEL; s += 256) {
        int e = topi[s];
        int p = atomicAdd(&cnt[e], 1);
        lists[e * 1024 + p] = s;
    }
}

// ---------------- s1/s3: s[slot,r] = SCALING * t[tok,:] . a[e,r,:] ----------------
__global__ __launch_bounds__(256) void s13_k(const float* __restrict__ t,
                                             const float* __restrict__ a1,
                                             const float* __restrict__ a3,
                                             const int* __restrict__ topi,
                                             float* __restrict__ s1,
                                             float* __restrict__ s3) {
    int tok = blockIdx.x;
    int w = threadIdx.x >> 6, lane = threadIdx.x & 63;
    int slot = tok * 2 + (w >> 1);
    int e = topi[slot];
    const float* ap = (w & 1) ? a3 : a1;
    float* sp = (w & 1) ? s3 : s1;
    const float* tr = t + (size_t)tok * DD;
    float tv[16];
    #pragma unroll
    for (int i = 0; i < 16; i++) tv[i] = tr[lane + 64 * i];
    const float* ab = ap + (size_t)e * RR * DD;
    #pragma unroll
    for (int r = 0; r < RR; r++) {
        const float* ar = ab + (size_t)r * DD;
        float c = 0.f;
        #pragma unroll
        for (int i = 0; i < 16; i++) c = fmaf(tv[i], ar[lane + 64 * i], c);
        #pragma unroll
        for (int o = 32; o > 0; o >>= 1) c += __shfl_down(c, o);
        if (lane == 0) sp[slot * RR + r] = SCALING * c;
    }
}

// ---- expert-major LoRA-up delta + SwiGLU: actb[slot,f] = silu(h1+d1)*(h3+d3) ------
// grid (FF/DFC, EE), 256 threads = 2 groups of 128; group g handles slots g, g+2, ...
__global__ __launch_bounds__(256) void delta_act_k(const float* __restrict__ b1,
                                                   const float* __restrict__ b3,
                                                   const float* __restrict__ s1,
                                                   const float* __restrict__ s3,
                                                   const int* __restrict__ lists,
                                                   const int* __restrict__ counts,
                                                   const u16* __restrict__ hb,
                                                   u16* __restrict__ actb) {
    int e = blockIdx.y, f0 = blockIdx.x * DFC;
    __shared__ float bL[2][16 * 132];     // [tensor][r*132 + f]
    __shared__ float sG[2][32 * 16];      // [tensor][slot_local*16 + r]
    int tid = threadIdx.x;
    int g = tid >> 7, f = tid & 127;
    {
        const float* bsrc1 = b1 + ((size_t)e * FF + f0) * RR;
        const float* bsrc3 = b3 + ((size_t)e * FF + f0) * RR;
        for (int i = tid; i < DFC * 16; i += 256) {
            int fi = i >> 4, r = i & 15;
            bL[0][r * 132 + fi] = bsrc1[i];
            bL[1][r * 132 + fi] = bsrc3[i];
        }
    }
    int n = counts[e];
    const int* lp = lists + e * 1024;
    for (int gb = 0; gb < n; gb += 32) {
        int gn = min(32, n - gb);
        __syncthreads();   // bL ready (1st) / sG free (later)
        {
            int sl_l = (tid & 127) >> 2, q = tid & 3;
            const float* ssrc = g ? s3 : s1;
            if (sl_l < gn) {
                int slot = lp[gb + sl_l];
                *(float4*)&sG[g][sl_l * 16 + q * 4] = *(const float4*)&ssrc[slot * RR + q * 4];
            }
        }
        __syncthreads();
        for (int ii = g; ii < gn; ii += 2) {
            int slot = lp[gb + ii];
            int tok = slot >> 1;
            const float* sp1 = &sG[0][ii * 16];
            const float* sp3 = &sG[1][ii * 16];
            float d1 = 0.f, d3 = 0.f;
            #pragma unroll
            for (int r = 0; r < RR; r++) {
                d1 = fmaf(sp1[r], bL[0][r * 132 + f], d1);
                d3 = fmaf(sp3[r], bL[1][r * 132 + f], d3);
            }
            float h1 = b2f(hb[(size_t)tok * (2 * FF) + f0 + f]) + d1;
            float h3 = b2f(hb[(size_t)tok * (2 * FF) + FF + f0 + f]) + d3;
            float sig = 1.f / (1.f + expf(-h1));
            actb[(size_t)slot * FF + f0 + f] = f2b(h1 * sig * h3);
        }
    }
}

// ---------------- generic NT GEMM, 64x128 tile, BK=32, 3-deep pipelined LDS ----------
// C[m,n] = sum_k A[m,k]*B[n,k]; A[M,K], B[N,K] bf16 (ld=K).
// SPLITK>1: blockIdx.z = K-chunk, fp32 partial planes C[z][M][N].
// BF16OUT: single full-K pass, bf16 C.
template<int SPLITK, bool BF16OUT>
__global__ __launch_bounds__(256) void gemm_nt(const u16* __restrict__ A,
                                               const u16* __restrict__ B,
                                               void* __restrict__ Cv,
                                               int M, int N, int K) {
    __shared__ u16 As[3][64 * 32];
    __shared__ u16 Bs[3][128 * 32];
    int tid = threadIdx.x;
    int w = tid >> 6, lane = tid & 63;
    int wr = w >> 1, wc = w & 1;            // wave tile: 32(M) x 64(N)
    int lr = lane & 15, ks = lane >> 4;
    int z = (SPLITK > 1) ? blockIdx.z : 0;
    int kc = K / SPLITK;
    int k0s = z * kc;
    int nk = kc / 32;
    int m0 = blockIdx.y * 64, n0 = blockIdx.x * 128;

    int row = tid >> 2;            // 0..63
    int inb = (tid & 3) * 16;
    size_t rb = (size_t)K * 2;
    const char* Ag  = (const char*)A + (size_t)(m0 + row) * rb + inb + (size_t)k0s * 2;
    const char* Bg  = (const char*)B + (size_t)(n0 + row) * rb + inb + (size_t)k0s * 2;
    const char* Bg2 = Bg + 64 * rb;

    floatx4 zero4 = {0.f, 0.f, 0.f, 0.f};
    floatx4 acc[2][4];
    #pragma unroll
    for (int i = 0; i < 2; i++)
        #pragma unroll
        for (int j = 0; j < 4; j++) acc[i][j] = zero4;

    auto stage = [&](int buf, int kt) {
        size_t kb = (size_t)kt * 64;   // 32 elems * 2B
        gl_lds16(Ag + kb, &As[buf][w * 512]);
        gl_lds16(Bg + kb, &Bs[buf][w * 512]);
        gl_lds16(Bg2 + kb, &Bs[buf][2048 + w * 512]);
    };
    auto compute = [&](int buf) {
        bhalf8 af[2], bf[4];
        #pragma unroll
        for (int i = 0; i < 2; i++)
            af[i] = *(const bhalf8*)&As[buf][(wr * 32 + i * 16 + lr) * 32 + ks * 8];
        #pragma unroll
        for (int j = 0; j < 4; j++)
            bf[j] = *(const bhalf8*)&Bs[buf][(wc * 64 + j * 16 + lr) * 32 + ks * 8];
        #pragma unroll
        for (int i = 0; i < 2; i++)
            #pragma unroll
            for (int j = 0; j < 4; j++)
                acc[i][j] = __builtin_amdgcn_mfma_f32_16x16x32_bf16(af[i], bf[j], acc[i][j], 0, 0, 0);
    };

    // prologue: 2 stages in flight, wait own stage0 (3 newest may fly), all-waves barrier
    stage(0, 0);
    stage(1, 1);
    asm volatile("s_waitcnt vmcnt(3)" ::: "memory");
    __builtin_amdgcn_s_barrier();

    int cur = 0;
    for (int kt = 0; kt < nk; ++kt) {
        int pre = cur + 2; if (pre >= 3) pre -= 3;
        if (kt + 2 < nk) stage(pre, kt + 2);   // issue 2-ahead (overlaps this compute + next)
        compute(cur);
        // drain own LDS reads so next iteration's stage can't overwrite live data,
        // then let one full stage (3 loads) remain in flight across the barrier.
        asm volatile("s_waitcnt lgkmcnt(0)" ::: "memory");
        if (kt + 1 < nk) {
            if (kt + 2 < nk) asm volatile("s_waitcnt vmcnt(3)" ::: "memory");
            else             asm volatile("s_waitcnt vmcnt(0)" ::: "memory");
            __builtin_amdgcn_s_barrier();
        }
        cur = (cur + 1 == 3) ? 0 : cur + 1;
    }

    int crow = (lane >> 4) * 4;
    #pragma unroll
    for (int i = 0; i < 2; i++) {
        #pragma unroll
        for (int j = 0; j < 4; j++) {
            int r0 = m0 + wr * 32 + i * 16 + crow;
            int c0 = n0 + wc * 64 + j * 16 + lr;
            if (BF16OUT) {
                u16* Cb = (u16*)Cv;
                #pragma unroll
                for (int mm = 0; mm < 4; mm++)
                    Cb[(size_t)(r0 + mm) * N + c0] = f2b(acc[i][j][mm]);
            } else {
                float* Cf = (float*)Cv + (size_t)z * M * N;
                #pragma unroll
                for (int mm = 0; mm < 4; mm++)
                    Cf[(size_t)(r0 + mm) * N + c0] = acc[i][j][mm];
            }
        }
    }
}

// ---------------- s2[slot,r] = SCALING * act[slot,:] . a2[e,r,:]  (bf16 act) --------
__global__ __launch_bounds__(256) void s2_k(const u16* __restrict__ actb,
                                            const float* __restrict__ a2,
                                            const int* __restrict__ topi,
                                            float* __restrict__ s2) {
    int slot = blockIdx.x;
    int e = topi[slot];
    const u16* ar = actb + (size_t)slot * FF;
    int wave = threadIdx.x >> 6, lane = threadIdx.x & 63;
    float av[64];
    #pragma unroll
    for (int i = 0; i < 16; i++) {
        ushort4 u = *(const ushort4*)(ar + lane * 4 + 256 * i);
        av[i * 4 + 0] = b2f(u.x); av[i * 4 + 1] = b2f(u.y);
        av[i * 4 + 2] = b2f(u.z); av[i * 4 + 3] = b2f(u.w);
    }
    #pragma unroll
    for (int rr = 0; rr < 4; rr++) {
        int r = wave * 4 + rr;
        const float* a2p = a2 + ((size_t)e * RR + r) * FF;
        float c = 0.f;
        #pragma unroll
        for (int i = 0; i < 16; i++) {
            float4 w4 = *(const float4*)(a2p + lane * 4 + 256 * i);
            c = fmaf(av[i * 4 + 0], w4.x, c);
            c = fmaf(av[i * 4 + 1], w4.y, c);
            c = fmaf(av[i * 4 + 2], w4.z, c);
            c = fmaf(av[i * 4 + 3], w4.w, c);
        }
        #pragma unroll
        for (int o = 32; o > 0; o >>= 1) c += __shfl_down(c, o);
        if (lane == 0) s2[slot * RR + r] = SCALING * c;
    }
}

// ---------------- combine: split-K partials + LoRA-down + expert weights ----------------
__global__ __launch_bounds__(256) void combine_k(const float* __restrict__ downP,
                                                 const float* __restrict__ s2,
                                                 const float* __restrict__ b2,
                                                 const float* __restrict__ topw,
                                                 const int* __restrict__ topi,
                                                 float* __restrict__ out) {
    int tok = blockIdx.x;
    for (int d = threadIdx.x; d < DD; d += 256) {
        float o = 0.f;
        #pragma unroll
        for (int k = 0; k < KKSEL; k++) {
            int slot = tok * KKSEL + k;
            int e = topi[slot];
            float w = topw[slot];
            float v = 0.f;
            #pragma unroll
            for (int zz = 0; zz < 4; zz++)
                v += downP[(size_t)zz * (TT * KKSEL) * DD + (size_t)slot * DD + d];
            const float* b2p = b2 + ((size_t)e * DD + d) * RR;
            const float* s2p = s2 + slot * RR;
            float l = 0.f;
            #pragma unroll
            for (int r = 0; r < RR; r++) l = fmaf(s2p[r], b2p[r], l);
            o += w * (v + l);
        }
        out[(size_t)tok * DD + d] = o;
    }
}

extern "C" void kernel_launch(void* const* d_in, const int* in_sizes, int n_in,
                              void* d_out, int out_size, void* d_ws, size_t ws_size,
                              hipStream_t stream) {
    const float* x  = (const float*)d_in[0];
    const float* nw = (const float*)d_in[1];
    const float* w1 = (const float*)d_in[2];
    const float* w3 = (const float*)d_in[3];
    const float* w2 = (const float*)d_in[4];
    const float* gw = (const float*)d_in[5];
    const float* a1 = (const float*)d_in[6];
    const float* b1 = (const float*)d_in[7];
    const float* a3 = (const float*)d_in[8];
    const float* b3 = (const float*)d_in[9];
    const float* a2 = (const float*)d_in[10];
    const float* b2 = (const float*)d_in[11];
    float* out = (float*)d_out;

    // workspace layout (~60 MB), all chunks 16B-aligned
    float* t     = (float*)d_ws;                          // 512*1024 f32
    float* downP = t + (size_t)TT * DD;                   // 4*1024*1024 f32
    float* s1    = downP + (size_t)4 * TT * KKSEL * DD;
    float* s3    = s1 + (size_t)TT * KKSEL * RR;
    float* s2    = s3 + (size_t)TT * KKSEL * RR;
    float* topw  = s2 + (size_t)TT * KKSEL * RR;
    int*   topi  = (int*)(topw + TT * KKSEL);
    int*   lists = topi + TT * KKSEL;                     // 8*1024
    int*   counts= lists + EE * 1024;                     // 16
    u16*   tb    = (u16*)(counts + 16);                   // 512*1024
    u16*   wB    = tb + (size_t)TT * DD;                  // [w1b | w3b] 8192*1024
    u16*   w2b   = wB + (size_t)2 * FF * DD;              // 1024*4096
    u16*   hb    = w2b + (size_t)DD * FF;                 // 512 * 8192 (h1|h3 per token)
    u16*   actb  = hb + (size_t)TT * 2 * FF;              // 1024*4096

    f2b_k<<<2048, 256, 0, stream>>>(w1, wB, FF * DD);
    f2b_k<<<2048, 256, 0, stream>>>(w3, wB + (size_t)FF * DD, FF * DD);
    f2b_k<<<2048, 256, 0, stream>>>(w2, w2b, DD * FF);
    rmsnorm_k<<<TT, 256, 0, stream>>>(x, nw, t, tb);
    router_k<<<TT, 64, 0, stream>>>(t, gw, topw, topi);
    build_lists_k<<<1, 256, 0, stream>>>(topi, lists, counts);
    s13_k<<<TT, 256, 0, stream>>>(t, a1, a3, topi, s1, s3);
    // h[tok, 0:4096]=t@w1^T, h[tok, 4096:8192]=t@w3^T  (flat N=8192, 512 blocks)
    gemm_nt<1, true><<<dim3(2 * FF / 128, TT / 64), 256, 0, stream>>>(
        tb, wB, hb, TT, 2 * FF, DD);
    delta_act_k<<<dim3(FF / DFC, EE), 256, 0, stream>>>(
        b1, b3, s1, s3, lists, counts, hb, actb);
    s2_k<<<TT * KKSEL, 256, 0, stream>>>(actb, a2, topi, s2);
    // down partials: split-K=4, 512 blocks
    gemm_nt<4, false><<<dim3(DD / 128, (TT * KKSEL) / 64, 4), 256, 0, stream>>>(
        actb, w2b, downP, TT * KKSEL, DD, FF);
    combine_k<<<TT, 256, 0, stream>>>(downP, s2, b2, topw, topi, out);
}

// Round 7
// 127.484 us; speedup vs baseline: 1.1784x; 1.1784x over previous
//
#include <hip/hip_runtime.h>
#include <hip/hip_bf16.h>
#include <math.h>

// Problem constants (B=1)
#define TT 512      // tokens = B*S
#define DD 1024     // model dim
#define FF 4096     // ffn dim
#define EE 8        // experts
#define RR 16       // lora rank
#define KKSEL 2     // top-k
#define SCALING 2.0f
#define EPSV 1e-6f
#define DFC 128     // delta kernel f-chunk
#define SCHUNK 32   // delta kernel slot-chunk

typedef unsigned short u16;
typedef short bhalf8 __attribute__((ext_vector_type(8)));
typedef float floatx4 __attribute__((ext_vector_type(4)));
typedef unsigned short u16x8 __attribute__((ext_vector_type(8)));

__device__ __forceinline__ u16 f2b(float f) {
    unsigned x = __builtin_bit_cast(unsigned, f);
    unsigned r = (x + 0x7fffu + ((x >> 16) & 1u)) >> 16;
    return (u16)r;
}
__device__ __forceinline__ float b2f(u16 b) {
    unsigned x = ((unsigned)b) << 16;
    return __builtin_bit_cast(float, x);
}

__device__ __forceinline__ void gl_lds16(const void* g, void* l) {
    __builtin_amdgcn_global_load_lds(
        (const __attribute__((address_space(1))) void*)g,
        (__attribute__((address_space(3))) void*)l, 16, 0, 0);
}

// ---------------- fp32 -> bf16 convert ----------------
__global__ __launch_bounds__(256) void f2b_k(const float* __restrict__ in,
                                             u16* __restrict__ out, int n) {
    int i = (blockIdx.x * 256 + threadIdx.x) * 4;
    int stride = gridDim.x * 256 * 4;
    for (; i < n; i += stride) {
        float4 v = *(const float4*)(in + i);
        ushort4 o = { f2b(v.x), f2b(v.y), f2b(v.z), f2b(v.w) };
        *(ushort4*)(out + i) = o;
    }
}

// ---------------- RMSNorm: x[T,D] -> t fp32 + bf16 ----------------
__global__ __launch_bounds__(256) void rmsnorm_k(const float* __restrict__ x,
                                                 const float* __restrict__ nw,
                                                 float* __restrict__ t,
                                                 u16* __restrict__ tb) {
    int tok = blockIdx.x;
    const float* xr = x + (size_t)tok * DD;
    float ss = 0.f;
    for (int d = threadIdx.x; d < DD; d += 256) { float v = xr[d]; ss += v * v; }
    __shared__ float red[4];
    #pragma unroll
    for (int o = 32; o > 0; o >>= 1) ss += __shfl_down(ss, o);
    int wave = threadIdx.x >> 6, lane = threadIdx.x & 63;
    if (lane == 0) red[wave] = ss;
    __syncthreads();
    if (threadIdx.x == 0) {
        float s = red[0] + red[1] + red[2] + red[3];
        red[0] = rsqrtf(s * (1.0f / DD) + EPSV);
    }
    __syncthreads();
    float rs = red[0];
    for (int d = threadIdx.x; d < DD; d += 256) {
        float v = xr[d] * rs * nw[d];
        t[(size_t)tok * DD + d] = v;
        tb[(size_t)tok * DD + d] = f2b(v);
    }
}

// ---------------- Router ----------------
__global__ __launch_bounds__(64) void router_k(const float* __restrict__ t,
                                               const float* __restrict__ gw,
                                               float* __restrict__ topw,
                                               int* __restrict__ topi) {
    int tok = blockIdx.x;
    int lane = threadIdx.x;
    const float* tr = t + (size_t)tok * DD;
    float acc[EE];
    #pragma unroll
    for (int e = 0; e < EE; e++) acc[e] = 0.f;
    for (int d = lane; d < DD; d += 64) {
        float tv = tr[d];
        #pragma unroll
        for (int e = 0; e < EE; e++) acc[e] = fmaf(tv, gw[(size_t)e * DD + d], acc[e]);
    }
    #pragma unroll
    for (int e = 0; e < EE; e++) {
        #pragma unroll
        for (int o = 32; o > 0; o >>= 1) acc[e] += __shfl_down(acc[e], o);
    }
    if (lane == 0) {
        float m = acc[0];
        #pragma unroll
        for (int e = 1; e < EE; e++) m = fmaxf(m, acc[e]);
        float p[EE];
        #pragma unroll
        for (int e = 0; e < EE; e++) p[e] = expf(acc[e] - m);
        int i0 = 0; float v0 = p[0];
        for (int e = 1; e < EE; e++) if (p[e] > v0) { v0 = p[e]; i0 = e; }
        int i1 = -1; float v1 = -1.f;
        for (int e = 0; e < EE; e++) { if (e == i0) continue; if (p[e] > v1) { v1 = p[e]; i1 = e; } }
        float inv = 1.f / (v0 + v1);
        topi[tok * KKSEL + 0] = i0;
        topi[tok * KKSEL + 1] = i1;
        topw[tok * KKSEL + 0] = v0 * inv;
        topw[tok * KKSEL + 1] = v1 * inv;
    }
}

// ---------------- bucket slots by expert ----------------
__global__ __launch_bounds__(256) void build_lists_k(const int* __restrict__ topi,
                                                     int* __restrict__ lists,
                                                     int* __restrict__ counts) {
    __shared__ int cnt[EE];
    int tid = threadIdx.x;
    if (tid < EE) cnt[tid] = 0;
    __syncthreads();
    for (int s = tid; s < TT * KKSEL; s += 256) atomicAdd(&cnt[topi[s]], 1);
    __syncthreads();
    if (tid < EE) { counts[tid] = cnt[tid]; cnt[tid] = 0; }
    __syncthreads();
    for (int s = tid; s < TT * KKSEL; s += 256) {
        int e = topi[s];
        int p = atomicAdd(&cnt[e], 1);
        lists[e * 1024 + p] = s;
    }
}

// ---------------- s1/s3: s[slot,r] = SCALING * t[tok,:] . a[e,r,:] ----------------
__global__ __launch_bounds__(256) void s13_k(const float* __restrict__ t,
                                             const float* __restrict__ a1,
                                             const float* __restrict__ a3,
                                             const int* __restrict__ topi,
                                             float* __restrict__ s1,
                                             float* __restrict__ s3) {
    int tok = blockIdx.x;
    int w = threadIdx.x >> 6, lane = threadIdx.x & 63;
    int slot = tok * 2 + (w >> 1);
    int e = topi[slot];
    const float* ap = (w & 1) ? a3 : a1;
    float* sp = (w & 1) ? s3 : s1;
    const float* tr = t + (size_t)tok * DD;
    float tv[16];
    #pragma unroll
    for (int i = 0; i < 16; i++) tv[i] = tr[lane + 64 * i];
    const float* ab = ap + (size_t)e * RR * DD;
    #pragma unroll
    for (int r = 0; r < RR; r++) {
        const float* ar = ab + (size_t)r * DD;
        float c = 0.f;
        #pragma unroll
        for (int i = 0; i < 16; i++) c = fmaf(tv[i], ar[lane + 64 * i], c);
        #pragma unroll
        for (int o = 32; o > 0; o >>= 1) c += __shfl_down(c, o);
        if (lane == 0) sp[slot * RR + r] = SCALING * c;
    }
}

// ---- expert-major LoRA-up delta + SwiGLU: actb[slot,f] = silu(h1+d1)*(h3+d3) ------
// grid (FF/DFC, EE, 32 slot-chunks); 256 threads = 2 groups of 128.
// Block (fb, e, z) handles slots lists[e][z*32 .. z*32+32) for f in [fb*128, fb*128+128).
__global__ __launch_bounds__(256) void delta_act_k(const float* __restrict__ b1,
                                                   const float* __restrict__ b3,
                                                   const float* __restrict__ s1,
                                                   const float* __restrict__ s3,
                                                   const int* __restrict__ lists,
                                                   const int* __restrict__ counts,
                                                   const u16* __restrict__ hb,
                                                   u16* __restrict__ actb) {
    int e = blockIdx.y, f0 = blockIdx.x * DFC;
    int st = blockIdx.z * SCHUNK;
    int n = counts[e];
    if (st >= n) return;
    int gn = min(SCHUNK, n - st);
    __shared__ float bL[2][16 * 132];     // [tensor][r*132 + f]
    __shared__ float sG[2][SCHUNK * 16];  // [tensor][slot_local*16 + r]
    __shared__ int   sSlot[SCHUNK];
    int tid = threadIdx.x;
    int g = tid >> 7, f = tid & 127;
    const int* lp = lists + e * 1024 + st;
    // load b chunk (transposed) + s vectors + slot ids
    {
        const float* bsrc1 = b1 + ((size_t)e * FF + f0) * RR;
        const float* bsrc3 = b3 + ((size_t)e * FF + f0) * RR;
        #pragma unroll
        for (int i = tid; i < DFC * 16; i += 256) {
            int fi = i >> 4, r = i & 15;
            bL[0][r * 132 + fi] = bsrc1[i];
            bL[1][r * 132 + fi] = bsrc3[i];
        }
        int sl_l = (tid & 127) >> 2, q = tid & 3;
        if (sl_l < gn) {
            int slot = lp[sl_l];
            const float* ssrc = g ? s3 : s1;
            *(float4*)&sG[g][sl_l * 16 + q * 4] = *(const float4*)&ssrc[slot * RR + q * 4];
            if (g == 0 && q == 0) sSlot[sl_l] = slot;
        }
    }
    __syncthreads();
    for (int ii = g; ii < gn; ii += 2) {
        int slot = sSlot[ii];
        int tok = slot >> 1;
        float h1b = b2f(hb[(size_t)tok * (2 * FF) + f0 + f]);
        float h3b = b2f(hb[(size_t)tok * (2 * FF) + FF + f0 + f]);
        const float* sp1 = &sG[0][ii * 16];
        const float* sp3 = &sG[1][ii * 16];
        float d1 = 0.f, d3 = 0.f;
        #pragma unroll
        for (int r = 0; r < RR; r++) {
            d1 = fmaf(sp1[r], bL[0][r * 132 + f], d1);
            d3 = fmaf(sp3[r], bL[1][r * 132 + f], d3);
        }
        float h1 = h1b + d1, h3 = h3b + d3;
        float sig = 1.f / (1.f + expf(-h1));
        actb[(size_t)slot * FF + f0 + f] = f2b(h1 * sig * h3);
    }
}

// ---------------- generic NT GEMM, 64x128 tile, BK=32, 3-deep pipelined LDS ----------
// C[m,n] = sum_k A[m,k]*B[n,k]; A[M,K], B[N,K] bf16 (ld=K).
// SPLITK>1: blockIdx.z = K-chunk, fp32 partial planes C[z][M][N].
// BF16OUT: single full-K pass, bf16 C.
template<int SPLITK, bool BF16OUT>
__global__ __launch_bounds__(256) void gemm_nt(const u16* __restrict__ A,
                                               const u16* __restrict__ B,
                                               void* __restrict__ Cv,
                                               int M, int N, int K) {
    __shared__ u16 As[3][64 * 32];
    __shared__ u16 Bs[3][128 * 32];
    int tid = threadIdx.x;
    int w = tid >> 6, lane = tid & 63;
    int wr = w >> 1, wc = w & 1;            // wave tile: 32(M) x 64(N)
    int lr = lane & 15, ks = lane >> 4;
    int z = (SPLITK > 1) ? blockIdx.z : 0;
    int kc = K / SPLITK;
    int k0s = z * kc;
    int nk = kc / 32;
    int m0 = blockIdx.y * 64, n0 = blockIdx.x * 128;

    int row = tid >> 2;            // 0..63
    int inb = (tid & 3) * 16;
    size_t rb = (size_t)K * 2;
    const char* Ag  = (const char*)A + (size_t)(m0 + row) * rb + inb + (size_t)k0s * 2;
    const char* Bg  = (const char*)B + (size_t)(n0 + row) * rb + inb + (size_t)k0s * 2;
    const char* Bg2 = Bg + 64 * rb;

    floatx4 zero4 = {0.f, 0.f, 0.f, 0.f};
    floatx4 acc[2][4];
    #pragma unroll
    for (int i = 0; i < 2; i++)
        #pragma unroll
        for (int j = 0; j < 4; j++) acc[i][j] = zero4;

    auto stage = [&](int buf, int kt) {
        size_t kb = (size_t)kt * 64;   // 32 elems * 2B
        gl_lds16(Ag + kb, &As[buf][w * 512]);
        gl_lds16(Bg + kb, &Bs[buf][w * 512]);
        gl_lds16(Bg2 + kb, &Bs[buf][2048 + w * 512]);
    };
    auto compute = [&](int buf) {
        bhalf8 af[2], bf[4];
        #pragma unroll
        for (int i = 0; i < 2; i++)
            af[i] = *(const bhalf8*)&As[buf][(wr * 32 + i * 16 + lr) * 32 + ks * 8];
        #pragma unroll
        for (int j = 0; j < 4; j++)
            bf[j] = *(const bhalf8*)&Bs[buf][(wc * 64 + j * 16 + lr) * 32 + ks * 8];
        #pragma unroll
        for (int i = 0; i < 2; i++)
            #pragma unroll
            for (int j = 0; j < 4; j++)
                acc[i][j] = __builtin_amdgcn_mfma_f32_16x16x32_bf16(af[i], bf[j], acc[i][j], 0, 0, 0);
    };

    // prologue: 2 stages in flight, wait own stage0 (3 newest may fly), all-waves barrier
    stage(0, 0);
    stage(1, 1);
    asm volatile("s_waitcnt vmcnt(3)" ::: "memory");
    __builtin_amdgcn_s_barrier();

    int cur = 0;
    for (int kt = 0; kt < nk; ++kt) {
        int pre = cur + 2; if (pre >= 3) pre -= 3;
        if (kt + 2 < nk) stage(pre, kt + 2);   // issue 2-ahead (overlaps this compute + next)
        compute(cur);
        // drain own LDS reads so next iteration's stage can't overwrite live data,
        // then let one full stage (3 loads) remain in flight across the barrier.
        asm volatile("s_waitcnt lgkmcnt(0)" ::: "memory");
        if (kt + 1 < nk) {
            if (kt + 2 < nk) asm volatile("s_waitcnt vmcnt(3)" ::: "memory");
            else             asm volatile("s_waitcnt vmcnt(0)" ::: "memory");
            __builtin_amdgcn_s_barrier();
        }
        cur = (cur + 1 == 3) ? 0 : cur + 1;
    }

    int crow = (lane >> 4) * 4;
    #pragma unroll
    for (int i = 0; i < 2; i++) {
        #pragma unroll
        for (int j = 0; j < 4; j++) {
            int r0 = m0 + wr * 32 + i * 16 + crow;
            int c0 = n0 + wc * 64 + j * 16 + lr;
            if (BF16OUT) {
                u16* Cb = (u16*)Cv;
                #pragma unroll
                for (int mm = 0; mm < 4; mm++)
                    Cb[(size_t)(r0 + mm) * N + c0] = f2b(acc[i][j][mm]);
            } else {
                float* Cf = (float*)Cv + (size_t)z * M * N;
                #pragma unroll
                for (int mm = 0; mm < 4; mm++)
                    Cf[(size_t)(r0 + mm) * N + c0] = acc[i][j][mm];
            }
        }
    }
}

// ---------------- s2[slot,r] = SCALING * act[slot,:] . a2[e,r,:]  (bf16 act) --------
__global__ __launch_bounds__(256) void s2_k(const u16* __restrict__ actb,
                                            const float* __restrict__ a2,
                                            const int* __restrict__ topi,
                                            float* __restrict__ s2) {
    int slot = blockIdx.x;
    int e = topi[slot];
    const u16* ar = actb + (size_t)slot * FF;
    int wave = threadIdx.x >> 6, lane = threadIdx.x & 63;
    float av[64];
    #pragma unroll
    for (int i = 0; i < 16; i++) {
        ushort4 u = *(const ushort4*)(ar + lane * 4 + 256 * i);
        av[i * 4 + 0] = b2f(u.x); av[i * 4 + 1] = b2f(u.y);
        av[i * 4 + 2] = b2f(u.z); av[i * 4 + 3] = b2f(u.w);
    }
    #pragma unroll
    for (int rr = 0; rr < 4; rr++) {
        int r = wave * 4 + rr;
        const float* a2p = a2 + ((size_t)e * RR + r) * FF;
        float c = 0.f;
        #pragma unroll
        for (int i = 0; i < 16; i++) {
            float4 w4 = *(const float4*)(a2p + lane * 4 + 256 * i);
            c = fmaf(av[i * 4 + 0], w4.x, c);
            c = fmaf(av[i * 4 + 1], w4.y, c);
            c = fmaf(av[i * 4 + 2], w4.z, c);
            c = fmaf(av[i * 4 + 3], w4.w, c);
        }
        #pragma unroll
        for (int o = 32; o > 0; o >>= 1) c += __shfl_down(c, o);
        if (lane == 0) s2[slot * RR + r] = SCALING * c;
    }
}

// ---------------- combine: split-K partials + LoRA-down + expert weights ----------------
__global__ __launch_bounds__(256) void combine_k(const float* __restrict__ downP,
                                                 const float* __restrict__ s2,
                                                 const float* __restrict__ b2,
                                                 const float* __restrict__ topw,
                                                 const int* __restrict__ topi,
                                                 float* __restrict__ out) {
    int tok = blockIdx.x;
    for (int d = threadIdx.x; d < DD; d += 256) {
        float o = 0.f;
        #pragma unroll
        for (int k = 0; k < KKSEL; k++) {
            int slot = tok * KKSEL + k;
            int e = topi[slot];
            float w = topw[slot];
            float v = 0.f;
            #pragma unroll
            for (int zz = 0; zz < 4; zz++)
                v += downP[(size_t)zz * (TT * KKSEL) * DD + (size_t)slot * DD + d];
            const float* b2p = b2 + ((size_t)e * DD + d) * RR;
            const float* s2p = s2 + slot * RR;
            float l = 0.f;
            #pragma unroll
            for (int r = 0; r < RR; r++) l = fmaf(s2p[r], b2p[r], l);
            o += w * (v + l);
        }
        out[(size_t)tok * DD + d] = o;
    }
}

extern "C" void kernel_launch(void* const* d_in, const int* in_sizes, int n_in,
                              void* d_out, int out_size, void* d_ws, size_t ws_size,
                              hipStream_t stream) {
    const float* x  = (const float*)d_in[0];
    const float* nw = (const float*)d_in[1];
    const float* w1 = (const float*)d_in[2];
    const float* w3 = (const float*)d_in[3];
    const float* w2 = (const float*)d_in[4];
    const float* gw = (const float*)d_in[5];
    const float* a1 = (const float*)d_in[6];
    const float* b1 = (const float*)d_in[7];
    const float* a3 = (const float*)d_in[8];
    const float* b3 = (const float*)d_in[9];
    const float* a2 = (const float*)d_in[10];
    const float* b2 = (const float*)d_in[11];
    float* out = (float*)d_out;

    // workspace layout (~60 MB), all chunks 16B-aligned
    float* t     = (float*)d_ws;                          // 512*1024 f32
    float* downP = t + (size_t)TT * DD;                   // 4*1024*1024 f32
    float* s1    = downP + (size_t)4 * TT * KKSEL * DD;
    float* s3    = s1 + (size_t)TT * KKSEL * RR;
    float* s2    = s3 + (size_t)TT * KKSEL * RR;
    float* topw  = s2 + (size_t)TT * KKSEL * RR;
    int*   topi  = (int*)(topw + TT * KKSEL);
    int*   lists = topi + TT * KKSEL;                     // 8*1024
    int*   counts= lists + EE * 1024;                     // 16
    u16*   tb    = (u16*)(counts + 16);                   // 512*1024
    u16*   wB    = tb + (size_t)TT * DD;                  // [w1b | w3b] 8192*1024
    u16*   w2b   = wB + (size_t)2 * FF * DD;              // 1024*4096
    u16*   hb    = w2b + (size_t)DD * FF;                 // 512 * 8192 (h1|h3 per token)
    u16*   actb  = hb + (size_t)TT * 2 * FF;              // 1024*4096

    f2b_k<<<2048, 256, 0, stream>>>(w1, wB, FF * DD);
    f2b_k<<<2048, 256, 0, stream>>>(w3, wB + (size_t)FF * DD, FF * DD);
    f2b_k<<<2048, 256, 0, stream>>>(w2, w2b, DD * FF);
    rmsnorm_k<<<TT, 256, 0, stream>>>(x, nw, t, tb);
    router_k<<<TT, 64, 0, stream>>>(t, gw, topw, topi);
    build_lists_k<<<1, 256, 0, stream>>>(topi, lists, counts);
    s13_k<<<TT, 256, 0, stream>>>(t, a1, a3, topi, s1, s3);
    // h[tok, 0:4096]=t@w1^T, h[tok, 4096:8192]=t@w3^T  (flat N=8192, 512 blocks)
    gemm_nt<1, true><<<dim3(2 * FF / 128, TT / 64), 256, 0, stream>>>(
        tb, wB, hb, TT, 2 * FF, DD);
    delta_act_k<<<dim3(FF / DFC, EE, 32), 256, 0, stream>>>(
        b1, b3, s1, s3, lists, counts, hb, actb);
    s2_k<<<TT * KKSEL, 256, 0, stream>>>(actb, a2, topi, s2);
    // down partials: split-K=4, 512 blocks
    gemm_nt<4, false><<<dim3(DD / 128, (TT * KKSEL) / 64, 4), 256, 0, stream>>>(
        actb, w2b, downP, TT * KKSEL, DD, FF);
    combine_k<<<TT, 256, 0, stream>>>(downP, s2, b2, topw, topi, out);
}

// Round 8
// 110.588 us; speedup vs baseline: 1.3584x; 1.1528x over previous
//
#include <hip/hip_runtime.h>
#include <hip/hip_bf16.h>
#include <math.h>

// Problem constants (B=1)
#define TT 512      // tokens = B*S
#define DD 1024     // model dim
#define FF 4096     // ffn dim
#define EE 8        // experts
#define RR 16       // lora rank
#define KKSEL 2     // top-k
#define SCALING 2.0f
#define EPSV 1e-6f
#define DFC 128     // delta kernel f-chunk
#define SCHUNK 32   // delta kernel slot-chunk

typedef unsigned short u16;
typedef short bhalf8 __attribute__((ext_vector_type(8)));
typedef float floatx4 __attribute__((ext_vector_type(4)));
typedef unsigned short u16x8 __attribute__((ext_vector_type(8)));

__device__ __forceinline__ u16 f2b(float f) {
    unsigned x = __builtin_bit_cast(unsigned, f);
    unsigned r = (x + 0x7fffu + ((x >> 16) & 1u)) >> 16;
    return (u16)r;
}
__device__ __forceinline__ float b2f(u16 b) {
    unsigned x = ((unsigned)b) << 16;
    return __builtin_bit_cast(float, x);
}

__device__ __forceinline__ void gl_lds16(const void* g, void* l) {
    __builtin_amdgcn_global_load_lds(
        (const __attribute__((address_space(1))) void*)g,
        (__attribute__((address_space(3))) void*)l, 16, 0, 0);
}

// ---------------- fp32 -> bf16 convert, all three weights (dst contiguous) ---------
__global__ __launch_bounds__(256) void f2b3_k(const float* __restrict__ w1,
                                              const float* __restrict__ w3,
                                              const float* __restrict__ w2,
                                              u16* __restrict__ dst) {
    const int FD = FF * DD;
    int i = (blockIdx.x * 256 + threadIdx.x) * 4;
    int stride = gridDim.x * 256 * 4;
    for (; i < 3 * FD; i += stride) {
        int seg = i / FD, off = i - seg * FD;
        const float* src = (seg == 0) ? w1 : ((seg == 1) ? w3 : w2);
        float4 v = *(const float4*)(src + off);
        ushort4 o = { f2b(v.x), f2b(v.y), f2b(v.z), f2b(v.w) };
        *(ushort4*)(dst + i) = o;
    }
}

// ---- prep: RMSNorm (t stays in LDS) + router top-2 + s1/s3 rank-16 projections ----
// grid = TT blocks, 256 threads (4 waves).
__global__ __launch_bounds__(256) void prep_k(const float* __restrict__ x,
                                              const float* __restrict__ nw,
                                              const float* __restrict__ gw,
                                              const float* __restrict__ a1,
                                              const float* __restrict__ a3,
                                              u16* __restrict__ tb,
                                              float* __restrict__ topw,
                                              int* __restrict__ topi,
                                              float* __restrict__ s1,
                                              float* __restrict__ s3) {
    int tok = blockIdx.x;
    __shared__ float tL[DD];
    __shared__ float red[12];
    __shared__ int sE[2];
    int tid = threadIdx.x, wave = tid >> 6, lane = tid & 63;
    const float* xr = x + (size_t)tok * DD;
    // RMSNorm
    float xv[4];
    float ss = 0.f;
    #pragma unroll
    for (int i = 0; i < 4; i++) { xv[i] = xr[tid + 256 * i]; ss += xv[i] * xv[i]; }
    #pragma unroll
    for (int o = 32; o > 0; o >>= 1) ss += __shfl_down(ss, o);
    if (lane == 0) red[wave] = ss;
    __syncthreads();
    if (tid == 0) red[8] = rsqrtf((red[0] + red[1] + red[2] + red[3]) * (1.0f / DD) + EPSV);
    __syncthreads();
    float rs = red[8];
    #pragma unroll
    for (int i = 0; i < 4; i++) {
        float v = xv[i] * rs * nw[tid + 256 * i];
        tL[tid + 256 * i] = v;
        tb[(size_t)tok * DD + tid + 256 * i] = f2b(v);
    }
    __syncthreads();
    // Router: wave w -> experts 2w, 2w+1
    {
        const float* g0 = gw + (size_t)(2 * wave) * DD;
        const float* g1 = g0 + DD;
        float a0 = 0.f, a1v = 0.f;
        for (int d = lane; d < DD; d += 64) {
            float tv = tL[d];
            a0 = fmaf(tv, g0[d], a0);
            a1v = fmaf(tv, g1[d], a1v);
        }
        #pragma unroll
        for (int o = 32; o > 0; o >>= 1) { a0 += __shfl_down(a0, o); a1v += __shfl_down(a1v, o); }
        if (lane == 0) { red[2 * wave] = a0; red[2 * wave + 1] = a1v; }
    }
    __syncthreads();
    if (tid == 0) {
        float m = red[0];
        #pragma unroll
        for (int e = 1; e < EE; e++) m = fmaxf(m, red[e]);
        float p[EE];
        #pragma unroll
        for (int e = 0; e < EE; e++) p[e] = expf(red[e] - m);
        int i0 = 0; float v0 = p[0];
        for (int e = 1; e < EE; e++) if (p[e] > v0) { v0 = p[e]; i0 = e; }
        int i1 = -1; float v1 = -1.f;
        for (int e = 0; e < EE; e++) { if (e == i0) continue; if (p[e] > v1) { v1 = p[e]; i1 = e; } }
        float inv = 1.f / (v0 + v1);
        topi[tok * KKSEL + 0] = i0;
        topi[tok * KKSEL + 1] = i1;
        topw[tok * KKSEL + 0] = v0 * inv;
        topw[tok * KKSEL + 1] = v1 * inv;
        sE[0] = i0; sE[1] = i1;
    }
    __syncthreads();
    // s1/s3: wave w -> slot-half (w>>1), tensor (w&1)
    {
        int half = wave >> 1, ten = wave & 1;
        int slot = tok * 2 + half;
        int e = sE[half];
        const float* ap = ten ? a3 : a1;
        float* sp = ten ? s3 : s1;
        float tv[16];
        #pragma unroll
        for (int i = 0; i < 16; i++) tv[i] = tL[lane + 64 * i];
        const float* ab = ap + (size_t)e * RR * DD;
        #pragma unroll
        for (int r = 0; r < RR; r++) {
            const float* ar = ab + (size_t)r * DD;
            float c = 0.f;
            #pragma unroll
            for (int i = 0; i < 16; i++) c = fmaf(tv[i], ar[lane + 64 * i], c);
            #pragma unroll
            for (int o = 32; o > 0; o >>= 1) c += __shfl_down(c, o);
            if (lane == 0) sp[slot * RR + r] = SCALING * c;
        }
    }
}

// ---------------- bucket slots by expert ----------------
__global__ __launch_bounds__(256) void build_lists_k(const int* __restrict__ topi,
                                                     int* __restrict__ lists,
                                                     int* __restrict__ counts) {
    __shared__ int cnt[EE];
    int tid = threadIdx.x;
    if (tid < EE) cnt[tid] = 0;
    __syncthreads();
    for (int s = tid; s < TT * KKSEL; s += 256) atomicAdd(&cnt[topi[s]], 1);
    __syncthreads();
    if (tid < EE) { counts[tid] = cnt[tid]; cnt[tid] = 0; }
    __syncthreads();
    for (int s = tid; s < TT * KKSEL; s += 256) {
        int e = topi[s];
        int p = atomicAdd(&cnt[e], 1);
        lists[e * 1024 + p] = s;
    }
}

// ---- expert-major LoRA-up delta + SwiGLU: actb[slot,f] = silu(h1+d1)*(h3+d3) ------
__global__ __launch_bounds__(256) void delta_act_k(const float* __restrict__ b1,
                                                   const float* __restrict__ b3,
                                                   const float* __restrict__ s1,
                                                   const float* __restrict__ s3,
                                                   const int* __restrict__ lists,
                                                   const int* __restrict__ counts,
                                                   const u16* __restrict__ hb,
                                                   u16* __restrict__ actb) {
    int e = blockIdx.y, f0 = blockIdx.x * DFC;
    int st = blockIdx.z * SCHUNK;
    int n = counts[e];
    if (st >= n) return;
    int gn = min(SCHUNK, n - st);
    __shared__ float bL[2][16 * 132];
    __shared__ float sG[2][SCHUNK * 16];
    __shared__ int   sSlot[SCHUNK];
    int tid = threadIdx.x;
    int g = tid >> 7, f = tid & 127;
    const int* lp = lists + e * 1024 + st;
    {
        const float* bsrc1 = b1 + ((size_t)e * FF + f0) * RR;
        const float* bsrc3 = b3 + ((size_t)e * FF + f0) * RR;
        #pragma unroll
        for (int i = tid; i < DFC * 16; i += 256) {
            int fi = i >> 4, r = i & 15;
            bL[0][r * 132 + fi] = bsrc1[i];
            bL[1][r * 132 + fi] = bsrc3[i];
        }
        int sl_l = (tid & 127) >> 2, q = tid & 3;
        if (sl_l < gn) {
            int slot = lp[sl_l];
            const float* ssrc = g ? s3 : s1;
            *(float4*)&sG[g][sl_l * 16 + q * 4] = *(const float4*)&ssrc[slot * RR + q * 4];
            if (g == 0 && q == 0) sSlot[sl_l] = slot;
        }
    }
    __syncthreads();
    for (int ii = g; ii < gn; ii += 2) {
        int slot = sSlot[ii];
        int tok = slot >> 1;
        float h1b = b2f(hb[(size_t)tok * (2 * FF) + f0 + f]);
        float h3b = b2f(hb[(size_t)tok * (2 * FF) + FF + f0 + f]);
        const float* sp1 = &sG[0][ii * 16];
        const float* sp3 = &sG[1][ii * 16];
        float d1 = 0.f, d3 = 0.f;
        #pragma unroll
        for (int r = 0; r < RR; r++) {
            d1 = fmaf(sp1[r], bL[0][r * 132 + f], d1);
            d3 = fmaf(sp3[r], bL[1][r * 132 + f], d3);
        }
        float h1 = h1b + d1, h3 = h3b + d3;
        float sig = 1.f / (1.f + expf(-h1));
        actb[(size_t)slot * FF + f0 + f] = f2b(h1 * sig * h3);
    }
}

// ---------------- generic NT GEMM, 64x128 tile, BK=32, 3-deep pipelined LDS ----------
template<int SPLITK, bool BF16OUT>
__global__ __launch_bounds__(256) void gemm_nt(const u16* __restrict__ A,
                                               const u16* __restrict__ B,
                                               void* __restrict__ Cv,
                                               int M, int N, int K) {
    __shared__ u16 As[3][64 * 32];
    __shared__ u16 Bs[3][128 * 32];
    int tid = threadIdx.x;
    int w = tid >> 6, lane = tid & 63;
    int wr = w >> 1, wc = w & 1;            // wave tile: 32(M) x 64(N)
    int lr = lane & 15, ks = lane >> 4;
    int z = (SPLITK > 1) ? blockIdx.z : 0;
    int kc = K / SPLITK;
    int k0s = z * kc;
    int nk = kc / 32;
    int m0 = blockIdx.y * 64, n0 = blockIdx.x * 128;

    int row = tid >> 2;            // 0..63
    int inb = (tid & 3) * 16;
    size_t rb = (size_t)K * 2;
    const char* Ag  = (const char*)A + (size_t)(m0 + row) * rb + inb + (size_t)k0s * 2;
    const char* Bg  = (const char*)B + (size_t)(n0 + row) * rb + inb + (size_t)k0s * 2;
    const char* Bg2 = Bg + 64 * rb;

    floatx4 zero4 = {0.f, 0.f, 0.f, 0.f};
    floatx4 acc[2][4];
    #pragma unroll
    for (int i = 0; i < 2; i++)
        #pragma unroll
        for (int j = 0; j < 4; j++) acc[i][j] = zero4;

    auto stage = [&](int buf, int kt) {
        size_t kb = (size_t)kt * 64;   // 32 elems * 2B
        gl_lds16(Ag + kb, &As[buf][w * 512]);
        gl_lds16(Bg + kb, &Bs[buf][w * 512]);
        gl_lds16(Bg2 + kb, &Bs[buf][2048 + w * 512]);
    };
    auto compute = [&](int buf) {
        bhalf8 af[2], bf[4];
        #pragma unroll
        for (int i = 0; i < 2; i++)
            af[i] = *(const bhalf8*)&As[buf][(wr * 32 + i * 16 + lr) * 32 + ks * 8];
        #pragma unroll
        for (int j = 0; j < 4; j++)
            bf[j] = *(const bhalf8*)&Bs[buf][(wc * 64 + j * 16 + lr) * 32 + ks * 8];
        #pragma unroll
        for (int i = 0; i < 2; i++)
            #pragma unroll
            for (int j = 0; j < 4; j++)
                acc[i][j] = __builtin_amdgcn_mfma_f32_16x16x32_bf16(af[i], bf[j], acc[i][j], 0, 0, 0);
    };

    stage(0, 0);
    stage(1, 1);
    asm volatile("s_waitcnt vmcnt(3)" ::: "memory");
    __builtin_amdgcn_s_barrier();

    int cur = 0;
    for (int kt = 0; kt < nk; ++kt) {
        int pre = cur + 2; if (pre >= 3) pre -= 3;
        if (kt + 2 < nk) stage(pre, kt + 2);
        compute(cur);
        asm volatile("s_waitcnt lgkmcnt(0)" ::: "memory");
        if (kt + 1 < nk) {
            if (kt + 2 < nk) asm volatile("s_waitcnt vmcnt(3)" ::: "memory");
            else             asm volatile("s_waitcnt vmcnt(0)" ::: "memory");
            __builtin_amdgcn_s_barrier();
        }
        cur = (cur + 1 == 3) ? 0 : cur + 1;
    }

    int crow = (lane >> 4) * 4;
    #pragma unroll
    for (int i = 0; i < 2; i++) {
        #pragma unroll
        for (int j = 0; j < 4; j++) {
            int r0 = m0 + wr * 32 + i * 16 + crow;
            int c0 = n0 + wc * 64 + j * 16 + lr;
            if (BF16OUT) {
                u16* Cb = (u16*)Cv;
                #pragma unroll
                for (int mm = 0; mm < 4; mm++)
                    Cb[(size_t)(r0 + mm) * N + c0] = f2b(acc[i][j][mm]);
            } else {
                float* Cf = (float*)Cv + (size_t)z * M * N;
                #pragma unroll
                for (int mm = 0; mm < 4; mm++)
                    Cf[(size_t)(r0 + mm) * N + c0] = acc[i][j][mm];
            }
        }
    }
}

// ---- s2 (both slots of a token) + mixed[t,f] = w0*act[2t,f] + w1*act[2t+1,f] -------
// grid = TT blocks; wave w: slot = 2t + (w>>1), r-range = (w&1)*8..+8
__global__ __launch_bounds__(256) void s2mix_k(const u16* __restrict__ actb,
                                               const float* __restrict__ a2,
                                               const int* __restrict__ topi,
                                               const float* __restrict__ topw,
                                               float* __restrict__ s2,
                                               u16* __restrict__ mixedb) {
    int tok = blockIdx.x;
    int tid = threadIdx.x, wave = tid >> 6, lane = tid & 63;
    int slot = tok * 2 + (wave >> 1);
    int e = topi[slot];
    const u16* ar = actb + (size_t)slot * FF;
    float av[64];
    #pragma unroll
    for (int i = 0; i < 16; i++) {
        ushort4 u = *(const ushort4*)(ar + lane * 4 + 256 * i);
        av[i * 4 + 0] = b2f(u.x); av[i * 4 + 1] = b2f(u.y);
        av[i * 4 + 2] = b2f(u.z); av[i * 4 + 3] = b2f(u.w);
    }
    #pragma unroll
    for (int rr = 0; rr < 8; rr++) {
        int r = (wave & 1) * 8 + rr;
        const float* a2p = a2 + ((size_t)e * RR + r) * FF;
        float c = 0.f;
        #pragma unroll
        for (int i = 0; i < 16; i++) {
            float4 w4 = *(const float4*)(a2p + lane * 4 + 256 * i);
            c = fmaf(av[i * 4 + 0], w4.x, c);
            c = fmaf(av[i * 4 + 1], w4.y, c);
            c = fmaf(av[i * 4 + 2], w4.z, c);
            c = fmaf(av[i * 4 + 3], w4.w, c);
        }
        #pragma unroll
        for (int o = 32; o > 0; o >>= 1) c += __shfl_down(c, o);
        if (lane == 0) s2[slot * RR + r] = SCALING * c;
    }
    // mixed (coalesced, independent of the above)
    float w0 = topw[tok * 2], w1v = topw[tok * 2 + 1];
    const u16* a0 = actb + (size_t)(tok * 2) * FF;
    const u16* a1p = a0 + FF;
    #pragma unroll
    for (int it = 0; it < 2; it++) {
        int f = tid * 8 + it * 2048;
        u16x8 v0 = *(const u16x8*)(a0 + f);
        u16x8 v1 = *(const u16x8*)(a1p + f);
        u16x8 o;
        #pragma unroll
        for (int q = 0; q < 8; q++)
            o[q] = f2b(w0 * b2f(v0[q]) + w1v * b2f(v1[q]));
        *(u16x8*)(mixedb + (size_t)tok * FF + f) = o;
    }
}

// ---- combine: out[t,d] = sum_z downP[z,t,d] + sum_k w_k * (s2[slot_k] . b2[e_k,d,:]) --
__global__ __launch_bounds__(256) void combine_k(const float* __restrict__ downP,
                                                 const float* __restrict__ s2,
                                                 const float* __restrict__ b2,
                                                 const float* __restrict__ topw,
                                                 const int* __restrict__ topi,
                                                 float* __restrict__ out) {
    int tok = blockIdx.x;
    for (int d = threadIdx.x; d < DD; d += 256) {
        float v = 0.f;
        #pragma unroll
        for (int zz = 0; zz < 8; zz++)
            v += downP[(size_t)zz * TT * DD + (size_t)tok * DD + d];
        #pragma unroll
        for (int k = 0; k < KKSEL; k++) {
            int slot = tok * KKSEL + k;
            int e = topi[slot];
            float w = topw[slot];
            const float* b2p = b2 + ((size_t)e * DD + d) * RR;
            const float* s2p = s2 + slot * RR;
            float l = 0.f;
            #pragma unroll
            for (int r = 0; r < RR; r++) l = fmaf(s2p[r], b2p[r], l);
            v += w * l;
        }
        out[(size_t)tok * DD + d] = v;
    }
}

extern "C" void kernel_launch(void* const* d_in, const int* in_sizes, int n_in,
                              void* d_out, int out_size, void* d_ws, size_t ws_size,
                              hipStream_t stream) {
    const float* x  = (const float*)d_in[0];
    const float* nw = (const float*)d_in[1];
    const float* w1 = (const float*)d_in[2];
    const float* w3 = (const float*)d_in[3];
    const float* w2 = (const float*)d_in[4];
    const float* gw = (const float*)d_in[5];
    const float* a1 = (const float*)d_in[6];
    const float* b1 = (const float*)d_in[7];
    const float* a3 = (const float*)d_in[8];
    const float* b3 = (const float*)d_in[9];
    const float* a2 = (const float*)d_in[10];
    const float* b2 = (const float*)d_in[11];
    float* out = (float*)d_out;

    // workspace layout (~61 MB), all chunks 16B-aligned
    float* downP = (float*)d_ws;                          // 8 * 512*1024 f32 (16MB)
    float* s1    = downP + (size_t)8 * TT * DD;
    float* s3    = s1 + (size_t)TT * KKSEL * RR;
    float* s2    = s3 + (size_t)TT * KKSEL * RR;
    float* topw  = s2 + (size_t)TT * KKSEL * RR;
    int*   topi  = (int*)(topw + TT * KKSEL);
    int*   lists = topi + TT * KKSEL;                     // 8*1024
    int*   counts= lists + EE * 1024;                     // 16
    u16*   tb    = (u16*)(counts + 16);                   // 512*1024
    u16*   wB    = tb + (size_t)TT * DD;                  // [w1b | w3b] 8192*1024
    u16*   w2b   = wB + (size_t)2 * FF * DD;              // 1024*4096 (contiguous after wB)
    u16*   hb    = w2b + (size_t)DD * FF;                 // 512*8192 (h1|h3 per token)
    u16*   actb  = hb + (size_t)TT * 2 * FF;              // 1024*4096
    u16*   mixedb= actb + (size_t)TT * KKSEL * FF;        // 512*4096

    f2b3_k<<<2048, 256, 0, stream>>>(w1, w3, w2, wB);
    prep_k<<<TT, 256, 0, stream>>>(x, nw, gw, a1, a3, tb, topw, topi, s1, s3);
    build_lists_k<<<1, 256, 0, stream>>>(topi, lists, counts);
    // h[tok, 0:4096]=t@w1^T, h[tok, 4096:8192]=t@w3^T  (flat N=8192, 512 blocks)
    gemm_nt<1, true><<<dim3(2 * FF / 128, TT / 64), 256, 0, stream>>>(
        tb, wB, hb, TT, 2 * FF, DD);
    delta_act_k<<<dim3(FF / DFC, EE, 32), 256, 0, stream>>>(
        b1, b3, s1, s3, lists, counts, hb, actb);
    s2mix_k<<<TT, 256, 0, stream>>>(actb, a2, topi, topw, s2, mixedb);
    // down base on mixed: M=512, split-K=8, 512 blocks
    gemm_nt<8, false><<<dim3(DD / 128, TT / 64, 8), 256, 0, stream>>>(
        mixedb, w2b, downP, TT, DD, FF);
    combine_k<<<TT, 256, 0, stream>>>(downP, s2, b2, topw, topi, out);
}

// Round 9
// 99.698 us; speedup vs baseline: 1.5068x; 1.1092x over previous
//
#include <hip/hip_runtime.h>
#include <hip/hip_bf16.h>
#include <math.h>

// Problem constants (B=1)
#define TT 512      // tokens = B*S
#define DD 1024     // model dim
#define FF 4096     // ffn dim
#define EE 8        // experts
#define RR 16       // lora rank
#define KKSEL 2     // top-k
#define SCALING 2.0f
#define EPSV 1e-6f
#define DFC 128     // delta kernel f-chunk
#define SCHUNK 32   // delta kernel slot-chunk

typedef unsigned short u16;
typedef short bhalf8 __attribute__((ext_vector_type(8)));
typedef float floatx4 __attribute__((ext_vector_type(4)));
typedef unsigned short u16x8 __attribute__((ext_vector_type(8)));

__device__ __forceinline__ u16 f2b(float f) {
    unsigned x = __builtin_bit_cast(unsigned, f);
    unsigned r = (x + 0x7fffu + ((x >> 16) & 1u)) >> 16;
    return (u16)r;
}
__device__ __forceinline__ float b2f(u16 b) {
    unsigned x = ((unsigned)b) << 16;
    return __builtin_bit_cast(float, x);
}

__device__ __forceinline__ void gl_lds16(const void* g, void* l) {
    __builtin_amdgcn_global_load_lds(
        (const __attribute__((address_space(1))) void*)g,
        (__attribute__((address_space(3))) void*)l, 16, 0, 0);
}

// ---- merged: prep (blocks 0..TT-1) + weight fp32->bf16 convert (blocks TT..TT+2047) ----
// prep: RMSNorm (t stays in LDS) + router top-2 + s1/s3 rank-16 projections.
__global__ __launch_bounds__(256) void prep_f2b_k(const float* __restrict__ x,
                                                  const float* __restrict__ nw,
                                                  const float* __restrict__ gw,
                                                  const float* __restrict__ a1,
                                                  const float* __restrict__ a3,
                                                  const float* __restrict__ w1,
                                                  const float* __restrict__ w3,
                                                  const float* __restrict__ w2,
                                                  u16* __restrict__ tb,
                                                  float* __restrict__ topw,
                                                  int* __restrict__ topi,
                                                  float* __restrict__ s1,
                                                  float* __restrict__ s3,
                                                  u16* __restrict__ wB) {
    __shared__ float tL[DD];
    __shared__ float red[12];
    __shared__ int sE[2];
    int tid = threadIdx.x;

    if (blockIdx.x >= TT) {
        // ---- weight convert: [w1 | w3 | w2] -> wB (bf16), 2048 blocks ----
        const int FD = FF * DD;
        int bid = blockIdx.x - TT;
        int i = (bid * 256 + tid) * 4;
        int stride = 2048 * 256 * 4;
        for (; i < 3 * FD; i += stride) {
            int seg = i / FD, off = i - seg * FD;
            const float* src = (seg == 0) ? w1 : ((seg == 1) ? w3 : w2);
            float4 v = *(const float4*)(src + off);
            ushort4 o = { f2b(v.x), f2b(v.y), f2b(v.z), f2b(v.w) };
            *(ushort4*)(wB + i) = o;
        }
        return;
    }

    int tok = blockIdx.x;
    int wave = tid >> 6, lane = tid & 63;
    const float* xr = x + (size_t)tok * DD;
    // RMSNorm
    float xv[4];
    float ss = 0.f;
    #pragma unroll
    for (int i = 0; i < 4; i++) { xv[i] = xr[tid + 256 * i]; ss += xv[i] * xv[i]; }
    #pragma unroll
    for (int o = 32; o > 0; o >>= 1) ss += __shfl_down(ss, o);
    if (lane == 0) red[wave] = ss;
    __syncthreads();
    if (tid == 0) red[8] = rsqrtf((red[0] + red[1] + red[2] + red[3]) * (1.0f / DD) + EPSV);
    __syncthreads();
    float rs = red[8];
    #pragma unroll
    for (int i = 0; i < 4; i++) {
        float v = xv[i] * rs * nw[tid + 256 * i];
        tL[tid + 256 * i] = v;
        tb[(size_t)tok * DD + tid + 256 * i] = f2b(v);
    }
    __syncthreads();
    // Router: wave w -> experts 2w, 2w+1
    {
        const float* g0 = gw + (size_t)(2 * wave) * DD;
        const float* g1 = g0 + DD;
        float a0 = 0.f, a1v = 0.f;
        for (int d = lane; d < DD; d += 64) {
            float tv = tL[d];
            a0 = fmaf(tv, g0[d], a0);
            a1v = fmaf(tv, g1[d], a1v);
        }
        #pragma unroll
        for (int o = 32; o > 0; o >>= 1) { a0 += __shfl_down(a0, o); a1v += __shfl_down(a1v, o); }
        if (lane == 0) { red[2 * wave] = a0; red[2 * wave + 1] = a1v; }
    }
    __syncthreads();
    if (tid == 0) {
        float m = red[0];
        #pragma unroll
        for (int e = 1; e < EE; e++) m = fmaxf(m, red[e]);
        float p[EE];
        #pragma unroll
        for (int e = 0; e < EE; e++) p[e] = expf(red[e] - m);
        int i0 = 0; float v0 = p[0];
        for (int e = 1; e < EE; e++) if (p[e] > v0) { v0 = p[e]; i0 = e; }
        int i1 = -1; float v1 = -1.f;
        for (int e = 0; e < EE; e++) { if (e == i0) continue; if (p[e] > v1) { v1 = p[e]; i1 = e; } }
        float inv = 1.f / (v0 + v1);
        topi[tok * KKSEL + 0] = i0;
        topi[tok * KKSEL + 1] = i1;
        topw[tok * KKSEL + 0] = v0 * inv;
        topw[tok * KKSEL + 1] = v1 * inv;
        sE[0] = i0; sE[1] = i1;
    }
    __syncthreads();
    // s1/s3: wave w -> slot-half (w>>1), tensor (w&1)
    {
        int half = wave >> 1, ten = wave & 1;
        int slot = tok * 2 + half;
        int e = sE[half];
        const float* ap = ten ? a3 : a1;
        float* sp = ten ? s3 : s1;
        float tv[16];
        #pragma unroll
        for (int i = 0; i < 16; i++) tv[i] = tL[lane + 64 * i];
        const float* ab = ap + (size_t)e * RR * DD;
        #pragma unroll
        for (int r = 0; r < RR; r++) {
            const float* ar = ab + (size_t)r * DD;
            float c = 0.f;
            #pragma unroll
            for (int i = 0; i < 16; i++) c = fmaf(tv[i], ar[lane + 64 * i], c);
            #pragma unroll
            for (int o = 32; o > 0; o >>= 1) c += __shfl_down(c, o);
            if (lane == 0) sp[slot * RR + r] = SCALING * c;
        }
    }
}

// ---- expert-major LoRA-up delta + SwiGLU: actb[slot,f] = silu(h1+d1)*(h3+d3) ------
__global__ __launch_bounds__(256) void delta_act_k(const float* __restrict__ b1,
                                                   const float* __restrict__ b3,
                                                   const float* __restrict__ s1,
                                                   const float* __restrict__ s3,
                                                   const int* __restrict__ lists,
                                                   const int* __restrict__ counts,
                                                   const u16* __restrict__ hb,
                                                   u16* __restrict__ actb) {
    int e = blockIdx.y, f0 = blockIdx.x * DFC;
    int st = blockIdx.z * SCHUNK;
    int n = counts[e];
    if (st >= n) return;
    int gn = min(SCHUNK, n - st);
    __shared__ float bL[2][16 * 132];
    __shared__ float sG[2][SCHUNK * 16];
    __shared__ int   sSlot[SCHUNK];
    int tid = threadIdx.x;
    int g = tid >> 7, f = tid & 127;
    const int* lp = lists + e * 1024 + st;
    {
        const float* bsrc1 = b1 + ((size_t)e * FF + f0) * RR;
        const float* bsrc3 = b3 + ((size_t)e * FF + f0) * RR;
        #pragma unroll
        for (int i = tid; i < DFC * 16; i += 256) {
            int fi = i >> 4, r = i & 15;
            bL[0][r * 132 + fi] = bsrc1[i];
            bL[1][r * 132 + fi] = bsrc3[i];
        }
        int sl_l = (tid & 127) >> 2, q = tid & 3;
        if (sl_l < gn) {
            int slot = lp[sl_l];
            const float* ssrc = g ? s3 : s1;
            *(float4*)&sG[g][sl_l * 16 + q * 4] = *(const float4*)&ssrc[slot * RR + q * 4];
            if (g == 0 && q == 0) sSlot[sl_l] = slot;
        }
    }
    __syncthreads();
    for (int ii = g; ii < gn; ii += 2) {
        int slot = sSlot[ii];
        int tok = slot >> 1;
        float h1b = b2f(hb[(size_t)tok * (2 * FF) + f0 + f]);
        float h3b = b2f(hb[(size_t)tok * (2 * FF) + FF + f0 + f]);
        const float* sp1 = &sG[0][ii * 16];
        const float* sp3 = &sG[1][ii * 16];
        float d1 = 0.f, d3 = 0.f;
        #pragma unroll
        for (int r = 0; r < RR; r++) {
            d1 = fmaf(sp1[r], bL[0][r * 132 + f], d1);
            d3 = fmaf(sp3[r], bL[1][r * 132 + f], d3);
        }
        float h1 = h1b + d1, h3 = h3b + d3;
        float sig = 1.f / (1.f + expf(-h1));
        actb[(size_t)slot * FF + f0 + f] = f2b(h1 * sig * h3);
    }
}

// ---------------- generic NT GEMM, 64x128 tile, BK=32, 3-deep pipelined LDS ----------
// LISTS: last y-row (y == gridDim.y-1) runs build_lists (x==0) instead of GEMM,
// overlapping the 1-block bucketing with the GEMM (no data dependency).
template<int SPLITK, bool BF16OUT, bool LISTS>
__global__ __launch_bounds__(256) void gemm_nt(const u16* __restrict__ A,
                                               const u16* __restrict__ B,
                                               void* __restrict__ Cv,
                                               int M, int N, int K,
                                               const int* __restrict__ topi,
                                               int* __restrict__ lists,
                                               int* __restrict__ counts) {
    __shared__ u16 As[3][64 * 32];
    __shared__ u16 Bs[3][128 * 32];
    int tid = threadIdx.x;

    if (LISTS && blockIdx.y == gridDim.y - 1) {
        if (blockIdx.x == 0) {
            int* cnt = (int*)&As[0][0];
            if (tid < EE) cnt[tid] = 0;
            __syncthreads();
            for (int s = tid; s < TT * KKSEL; s += 256) atomicAdd(&cnt[topi[s]], 1);
            __syncthreads();
            if (tid < EE) { counts[tid] = cnt[tid]; cnt[tid] = 0; }
            __syncthreads();
            for (int s = tid; s < TT * KKSEL; s += 256) {
                int e = topi[s];
                int p = atomicAdd(&cnt[e], 1);
                lists[e * 1024 + p] = s;
            }
        }
        return;
    }

    int w = tid >> 6, lane = tid & 63;
    int wr = w >> 1, wc = w & 1;            // wave tile: 32(M) x 64(N)
    int lr = lane & 15, ks = lane >> 4;
    int z = (SPLITK > 1) ? blockIdx.z : 0;
    int kc = K / SPLITK;
    int k0s = z * kc;
    int nk = kc / 32;
    int m0 = blockIdx.y * 64, n0 = blockIdx.x * 128;

    int row = tid >> 2;            // 0..63
    int inb = (tid & 3) * 16;
    size_t rb = (size_t)K * 2;
    const char* Ag  = (const char*)A + (size_t)(m0 + row) * rb + inb + (size_t)k0s * 2;
    const char* Bg  = (const char*)B + (size_t)(n0 + row) * rb + inb + (size_t)k0s * 2;
    const char* Bg2 = Bg + 64 * rb;

    floatx4 zero4 = {0.f, 0.f, 0.f, 0.f};
    floatx4 acc[2][4];
    #pragma unroll
    for (int i = 0; i < 2; i++)
        #pragma unroll
        for (int j = 0; j < 4; j++) acc[i][j] = zero4;

    auto stage = [&](int buf, int kt) {
        size_t kb = (size_t)kt * 64;   // 32 elems * 2B
        gl_lds16(Ag + kb, &As[buf][w * 512]);
        gl_lds16(Bg + kb, &Bs[buf][w * 512]);
        gl_lds16(Bg2 + kb, &Bs[buf][2048 + w * 512]);
    };
    auto compute = [&](int buf) {
        bhalf8 af[2], bf[4];
        #pragma unroll
        for (int i = 0; i < 2; i++)
            af[i] = *(const bhalf8*)&As[buf][(wr * 32 + i * 16 + lr) * 32 + ks * 8];
        #pragma unroll
        for (int j = 0; j < 4; j++)
            bf[j] = *(const bhalf8*)&Bs[buf][(wc * 64 + j * 16 + lr) * 32 + ks * 8];
        #pragma unroll
        for (int i = 0; i < 2; i++)
            #pragma unroll
            for (int j = 0; j < 4; j++)
                acc[i][j] = __builtin_amdgcn_mfma_f32_16x16x32_bf16(af[i], bf[j], acc[i][j], 0, 0, 0);
    };

    stage(0, 0);
    stage(1, 1);
    asm volatile("s_waitcnt vmcnt(3)" ::: "memory");
    __builtin_amdgcn_s_barrier();

    int cur = 0;
    for (int kt = 0; kt < nk; ++kt) {
        int pre = cur + 2; if (pre >= 3) pre -= 3;
        if (kt + 2 < nk) stage(pre, kt + 2);
        compute(cur);
        asm volatile("s_waitcnt lgkmcnt(0)" ::: "memory");
        if (kt + 1 < nk) {
            if (kt + 2 < nk) asm volatile("s_waitcnt vmcnt(3)" ::: "memory");
            else             asm volatile("s_waitcnt vmcnt(0)" ::: "memory");
            __builtin_amdgcn_s_barrier();
        }
        cur = (cur + 1 == 3) ? 0 : cur + 1;
    }

    int crow = (lane >> 4) * 4;
    #pragma unroll
    for (int i = 0; i < 2; i++) {
        #pragma unroll
        for (int j = 0; j < 4; j++) {
            int r0 = m0 + wr * 32 + i * 16 + crow;
            int c0 = n0 + wc * 64 + j * 16 + lr;
            if (BF16OUT) {
                u16* Cb = (u16*)Cv;
                #pragma unroll
                for (int mm = 0; mm < 4; mm++)
                    Cb[(size_t)(r0 + mm) * N + c0] = f2b(acc[i][j][mm]);
            } else {
                float* Cf = (float*)Cv + (size_t)z * M * N;
                #pragma unroll
                for (int mm = 0; mm < 4; mm++)
                    Cf[(size_t)(r0 + mm) * N + c0] = acc[i][j][mm];
            }
        }
    }
}

// ---- s2 (both slots of a token) + mixed[t,f] = w0*act[2t,f] + w1*act[2t+1,f] -------
__global__ __launch_bounds__(256) void s2mix_k(const u16* __restrict__ actb,
                                               const float* __restrict__ a2,
                                               const int* __restrict__ topi,
                                               const float* __restrict__ topw,
                                               float* __restrict__ s2,
                                               u16* __restrict__ mixedb) {
    int tok = blockIdx.x;
    int tid = threadIdx.x, wave = tid >> 6, lane = tid & 63;
    int slot = tok * 2 + (wave >> 1);
    int e = topi[slot];
    const u16* ar = actb + (size_t)slot * FF;
    float av[64];
    #pragma unroll
    for (int i = 0; i < 16; i++) {
        ushort4 u = *(const ushort4*)(ar + lane * 4 + 256 * i);
        av[i * 4 + 0] = b2f(u.x); av[i * 4 + 1] = b2f(u.y);
        av[i * 4 + 2] = b2f(u.z); av[i * 4 + 3] = b2f(u.w);
    }
    #pragma unroll
    for (int rr = 0; rr < 8; rr++) {
        int r = (wave & 1) * 8 + rr;
        const float* a2p = a2 + ((size_t)e * RR + r) * FF;
        float c = 0.f;
        #pragma unroll
        for (int i = 0; i < 16; i++) {
            float4 w4 = *(const float4*)(a2p + lane * 4 + 256 * i);
            c = fmaf(av[i * 4 + 0], w4.x, c);
            c = fmaf(av[i * 4 + 1], w4.y, c);
            c = fmaf(av[i * 4 + 2], w4.z, c);
            c = fmaf(av[i * 4 + 3], w4.w, c);
        }
        #pragma unroll
        for (int o = 32; o > 0; o >>= 1) c += __shfl_down(c, o);
        if (lane == 0) s2[slot * RR + r] = SCALING * c;
    }
    // mixed (coalesced, independent of the above)
    float w0 = topw[tok * 2], w1v = topw[tok * 2 + 1];
    const u16* a0 = actb + (size_t)(tok * 2) * FF;
    const u16* a1p = a0 + FF;
    #pragma unroll
    for (int it = 0; it < 2; it++) {
        int f = tid * 8 + it * 2048;
        u16x8 v0 = *(const u16x8*)(a0 + f);
        u16x8 v1 = *(const u16x8*)(a1p + f);
        u16x8 o;
        #pragma unroll
        for (int q = 0; q < 8; q++)
            o[q] = f2b(w0 * b2f(v0[q]) + w1v * b2f(v1[q]));
        *(u16x8*)(mixedb + (size_t)tok * FF + f) = o;
    }
}

// ---- combine: out[t,d] = sum_z downP[z,t,d] + sum_k w_k * (s2[slot_k] . b2[e_k,d,:]) --
__global__ __launch_bounds__(256) void combine_k(const float* __restrict__ downP,
                                                 const float* __restrict__ s2,
                                                 const float* __restrict__ b2,
                                                 const float* __restrict__ topw,
                                                 const int* __restrict__ topi,
                                                 float* __restrict__ out) {
    int tok = blockIdx.x;
    for (int d = threadIdx.x; d < DD; d += 256) {
        float v = 0.f;
        #pragma unroll
        for (int zz = 0; zz < 8; zz++)
            v += downP[(size_t)zz * TT * DD + (size_t)tok * DD + d];
        #pragma unroll
        for (int k = 0; k < KKSEL; k++) {
            int slot = tok * KKSEL + k;
            int e = topi[slot];
            float w = topw[slot];
            const float* b2p = b2 + ((size_t)e * DD + d) * RR;
            const float* s2p = s2 + slot * RR;
            float l = 0.f;
            #pragma unroll
            for (int r = 0; r < RR; r++) l = fmaf(s2p[r], b2p[r], l);
            v += w * l;
        }
        out[(size_t)tok * DD + d] = v;
    }
}

extern "C" void kernel_launch(void* const* d_in, const int* in_sizes, int n_in,
                              void* d_out, int out_size, void* d_ws, size_t ws_size,
                              hipStream_t stream) {
    const float* x  = (const float*)d_in[0];
    const float* nw = (const float*)d_in[1];
    const float* w1 = (const float*)d_in[2];
    const float* w3 = (const float*)d_in[3];
    const float* w2 = (const float*)d_in[4];
    const float* gw = (const float*)d_in[5];
    const float* a1 = (const float*)d_in[6];
    const float* b1 = (const float*)d_in[7];
    const float* a3 = (const float*)d_in[8];
    const float* b3 = (const float*)d_in[9];
    const float* a2 = (const float*)d_in[10];
    const float* b2 = (const float*)d_in[11];
    float* out = (float*)d_out;

    // workspace layout (~61 MB), all chunks 16B-aligned
    float* downP = (float*)d_ws;                          // 8 * 512*1024 f32 (16MB)
    float* s1    = downP + (size_t)8 * TT * DD;
    float* s3    = s1 + (size_t)TT * KKSEL * RR;
    float* s2    = s3 + (size_t)TT * KKSEL * RR;
    float* topw  = s2 + (size_t)TT * KKSEL * RR;
    int*   topi  = (int*)(topw + TT * KKSEL);
    int*   lists = topi + TT * KKSEL;                     // 8*1024
    int*   counts= lists + EE * 1024;                     // 16
    u16*   tb    = (u16*)(counts + 16);                   // 512*1024
    u16*   wB    = tb + (size_t)TT * DD;                  // [w1b | w3b | w2b] 3*4096*1024
    u16*   w2b   = wB + (size_t)2 * FF * DD;
    u16*   hb    = w2b + (size_t)DD * FF;                 // 512*8192 (h1|h3 per token)
    u16*   actb  = hb + (size_t)TT * 2 * FF;              // 1024*4096
    u16*   mixedb= actb + (size_t)TT * KKSEL * FF;        // 512*4096

    // prep (512 blocks) + weight convert (2048 blocks) in one launch
    prep_f2b_k<<<TT + 2048, 256, 0, stream>>>(
        x, nw, gw, a1, a3, w1, w3, w2, tb, topw, topi, s1, s3, wB);
    // h[tok, 0:4096]=t@w1^T, h[tok, 4096:8192]=t@w3^T (512 GEMM blocks)
    // + build_lists in the extra y-row (overlapped, no dependency)
    gemm_nt<1, true, true><<<dim3(2 * FF / 128, TT / 64 + 1), 256, 0, stream>>>(
        tb, wB, hb, TT, 2 * FF, DD, topi, lists, counts);
    delta_act_k<<<dim3(FF / DFC, EE, 32), 256, 0, stream>>>(
        b1, b3, s1, s3, lists, counts, hb, actb);
    s2mix_k<<<TT, 256, 0, stream>>>(actb, a2, topi, topw, s2, mixedb);
    // down base on mixed: M=512, split-K=8, 512 blocks
    gemm_nt<8, false, false><<<dim3(DD / 128, TT / 64, 8), 256, 0, stream>>>(
        mixedb, w2b, downP, TT, DD, FF, nullptr, nullptr, nullptr);
    combine_k<<<TT, 256, 0, stream>>>(downP, s2, b2, topw, topi, out);
}